// Round 1
// baseline (611.697 us; speedup 1.0000x reference)
//
#include <hip/hip_runtime.h>
#include <math.h>

#define NBINS   64
#define GROUPS  16
#define HIDDEN  128
#define EPSF    1e-6f

// B=2, C=16, H=W=1024; 32 images of 1M floats; 32x32 tiles of 32x32 elems.
#define IMG_ELEMS   (1024*1024)
#define F4_PER_ROW  256          // 1024 cols / 4
#define NIMG        32           // B*C

// ---------------------------------------------------------------------------
// Kernel 1: per image-row-chunk (32 rows): min/max partials + 32 tile sums.
// grid = NIMG*32 blocks, 256 threads. Thread t always reads float4 col t, so
// loads are perfectly coalesced AND thread t's data all lies in tile j=t>>3.
// ---------------------------------------------------------------------------
__global__ __launch_bounds__(256) void k_stats(
        const float* __restrict__ x,
        float* __restrict__ blocksum,   // [NIMG][32][32] tile sums
        float* __restrict__ pmin,       // [NIMG*32]
        float* __restrict__ pmax)       // [NIMG*32]
{
    const int bid = blockIdx.x;
    const int bc  = bid >> 5;   // image
    const int i   = bid & 31;   // row-chunk (tile row)
    const int t   = threadIdx.x;

    const float4* xin = (const float4*)(x + (size_t)bc * IMG_ELEMS);
    const int rowbase = (i * 32) * F4_PER_ROW;

    float s = 0.f, mn = INFINITY, mx = -INFINITY;
    #pragma unroll 4
    for (int r = 0; r < 32; ++r) {
        float4 v = xin[rowbase + r * F4_PER_ROW + t];
        s += (v.x + v.y) + (v.z + v.w);
        mn = fminf(mn, fminf(fminf(v.x, v.y), fminf(v.z, v.w)));
        mx = fmaxf(mx, fmaxf(fmaxf(v.x, v.y), fmaxf(v.z, v.w)));
    }

    __shared__ float ssum[256], smin[256], smax[256];
    ssum[t] = s; smin[t] = mn; smax[t] = mx;
    __syncthreads();

    // tile-sum reduce: 8 consecutive threads share tile j = t>>3
    if ((t & 7) < 4) ssum[t] += ssum[t + 4];
    __syncthreads();
    if ((t & 7) < 2) ssum[t] += ssum[t + 2];
    __syncthreads();
    if ((t & 7) == 0) {
        float tot = ssum[t] + ssum[t + 1];
        blocksum[bc * 1024 + i * 32 + (t >> 3)] = tot;
    }

    // block-wide min/max
    for (int st = 128; st > 0; st >>= 1) {
        __syncthreads();
        if (t < st) {
            smin[t] = fminf(smin[t], smin[t + st]);
            smax[t] = fmaxf(smax[t], smax[t + st]);
        }
    }
    __syncthreads();
    if (t == 0) { pmin[bid] = smin[0]; pmax[bid] = smax[0]; }
}

// ---------------------------------------------------------------------------
// Kernel 2: reduce 32 partials per image. grid = NIMG blocks, 64 threads.
// Lanes 32..63 duplicate lanes 0..31 (harmless for min/max).
// ---------------------------------------------------------------------------
__global__ __launch_bounds__(64) void k_minmax(
        const float* __restrict__ pmin, const float* __restrict__ pmax,
        float* __restrict__ gmin, float* __restrict__ gmax)
{
    const int bc = blockIdx.x;
    const int l  = threadIdx.x;
    float mn = pmin[bc * 32 + (l & 31)];
    float mx = pmax[bc * 32 + (l & 31)];
    #pragma unroll
    for (int st = 32; st > 0; st >>= 1) {
        mn = fminf(mn, __shfl_xor(mn, st, 64));
        mx = fmaxf(mx, __shfl_xor(mx, st, 64));
    }
    if (l == 0) { gmin[bc] = mn; gmax[bc] = mx; }
}

// ---------------------------------------------------------------------------
// Kernel 3: histogram -> cdf -> LUT net -> lut[16][64].  1 block, 256 thr.
// conv pad=2 on an H=1 input means only kernel row kh=2 contributes -> 1-D.
// LDS: dcdf 4KB + h1 32KB + sd 4KB + hist 256B ~= 40.3KB (< 64KB/block).
// ---------------------------------------------------------------------------
__global__ __launch_bounds__(256) void k_lut(
        const float* __restrict__ blocksum,
        const float* __restrict__ gmin, const float* __restrict__ gmax,
        const float* __restrict__ w1, const float* __restrict__ b1,
        const float* __restrict__ w2, const float* __restrict__ b2,
        const float* __restrict__ w3, const float* __restrict__ b3,
        float* __restrict__ lut)
{
    __shared__ float dcdf[GROUPS][NBINS];
    __shared__ float h1[HIDDEN][NBINS];
    __shared__ float sd[GROUPS][NBINS];
    __shared__ int   hist[NBINS];
    const int t = threadIdx.x;

    for (int o = t; o < GROUPS * NBINS; o += 256) ((float*)dcdf)[o] = 0.f;

    const float invden = 1.0f / (1024.0f + EPSF);
    for (int b = 0; b < 2; ++b) {
        for (int g = 0; g < GROUPS; ++g) {
            __syncthreads();
            if (t < NBINS) hist[t] = 0;
            __syncthreads();
            const int bc = b * GROUPS + g;
            const float mnv = gmin[bc];
            const float inv = 1.0f / (gmax[bc] - mnv + EPSF);
            #pragma unroll
            for (int it = 0; it < 4; ++it) {
                const int v = t + it * 256;
                float bmean = blocksum[bc * 1024 + v] * (1.0f / 1024.0f);
                float xs = (bmean - mnv) * inv;
                int idx = (int)rintf(xs * 63.0f);     // round-half-even, matches jnp.round
                idx = max(0, min(idx, 63));
                atomicAdd(&hist[idx], 1);
            }
            __syncthreads();
            if (t < NBINS) {
                int s = 0;
                for (int k = 0; k <= t; ++k) s += hist[k];
                dcdf[g][t] += 0.5f * (float)s * invden;   // mean over B=2
            }
        }
    }
    __syncthreads();

    // conv1: 16 -> 128 channels, 5 taps, ReLU
    for (int it = 0; it < 32; ++it) {
        const int o = t + it * 256;
        const int oc = o >> 6, k = o & 63;
        float acc = b1[oc];
        for (int ic = 0; ic < GROUPS; ++ic) {
            const float* wp = w1 + ((oc * GROUPS + ic) * 5 + 2) * 5;  // kh=2 row
            #pragma unroll
            for (int tap = 0; tap < 5; ++tap) {
                const int kk = k - 2 + tap;
                if (kk >= 0 && kk < NBINS) acc += wp[tap] * dcdf[ic][kk];
            }
        }
        h1[oc][k] = fmaxf(acc, 0.f);
    }
    __syncthreads();

    // conv2: depthwise 5 taps, ReLU — in-place over h1 via register staging
    float acc2[32];
    #pragma unroll
    for (int it = 0; it < 32; ++it) {
        const int o = t + it * 256;
        const int c = o >> 6, k = o & 63;
        const float* wp = w2 + c * 25 + 10;   // [c][0][2][*]
        float a = b2[c];
        #pragma unroll
        for (int tap = 0; tap < 5; ++tap) {
            const int kk = k - 2 + tap;
            if (kk >= 0 && kk < NBINS) a += wp[tap] * h1[c][kk];
        }
        acc2[it] = a;
    }
    __syncthreads();
    #pragma unroll
    for (int it = 0; it < 32; ++it) {
        const int o = t + it * 256;
        h1[o >> 6][o & 63] = fmaxf(acc2[it], 0.f);
    }
    __syncthreads();

    // conv3: 1x1, 128 -> 16, softplus
    #pragma unroll
    for (int it = 0; it < 4; ++it) {
        const int o = t + it * 256;
        const int g = o >> 6, k = o & 63;
        float acc = b3[g];
        for (int h = 0; h < HIDDEN; ++h) acc += w3[g * HIDDEN + h] * h1[h][k];
        sd[g][k] = fmaxf(acc, 0.f) + log1pf(expf(-fabsf(acc)));  // stable softplus
    }
    __syncthreads();

    // cumsum, normalize, add identity ramp
    if (t < GROUPS) {
        float run = 0.f;
        for (int k = 0; k < NBINS; ++k) { run += sd[t][k]; sd[t][k] = run; }
        const float invn = 1.0f / (run + EPSF);
        for (int k = 0; k < NBINS; ++k)
            lut[t * NBINS + k] = sd[t][k] * invn + (float)k * (1.0f / 63.0f);
    }
}

// ---------------------------------------------------------------------------
// Kernel 4: elementwise remap. grid = NIMG*64 blocks, 256 threads,
// 16 float4 per thread. LUT row (64 floats) in LDS.
// ---------------------------------------------------------------------------
__device__ __forceinline__ float remap1(float v, float mnv, float inv, float r,
                                        float aa, const float* lut_s)
{
    float x01 = (v - mnv) * inv;
    float pos = x01 * 63.0f;
    int il = (int)floorf(pos);
    il = max(0, min(il, 63));
    const int ih = min(il + 1, 63);
    const float w = pos - (float)il;
    const float vlo = lut_s[il];
    const float vhi = lut_s[ih];
    const float xe = fmaf(w, vhi - vlo, vlo);
    const float o01 = aa * xe + (1.0f - aa) * x01;
    return o01 * r + mnv;
}

__global__ __launch_bounds__(256) void k_apply(
        const float* __restrict__ x,
        const float* __restrict__ gmin, const float* __restrict__ gmax,
        const float* __restrict__ lut, const float* __restrict__ alpha,
        float* __restrict__ out)
{
    const int img  = blockIdx.x >> 6;
    const int part = blockIdx.x & 63;
    const int c    = img & 15;
    const int t    = threadIdx.x;

    __shared__ float lut_s[NBINS];
    if (t < NBINS) lut_s[t] = lut[c * NBINS + t];
    __syncthreads();

    const float mnv = gmin[img];
    const float mxv = gmax[img];
    const float r   = mxv - mnv;
    const float inv = 1.0f / (r + EPSF);
    const float aa  = 1.0f / (1.0f + expf(-alpha[0]));

    const size_t base4 = (size_t)img * (IMG_ELEMS / 4) + (size_t)part * 4096;
    const float4* xin = (const float4*)x;
    float4* o4 = (float4*)out;

    #pragma unroll 2
    for (int it = 0; it < 16; ++it) {
        const size_t f = base4 + (size_t)t + (size_t)it * 256;
        float4 v = xin[f];
        float4 w;
        w.x = remap1(v.x, mnv, inv, r, aa, lut_s);
        w.y = remap1(v.y, mnv, inv, r, aa, lut_s);
        w.z = remap1(v.z, mnv, inv, r, aa, lut_s);
        w.w = remap1(v.w, mnv, inv, r, aa, lut_s);
        o4[f] = w;
    }
}

// ---------------------------------------------------------------------------
extern "C" void kernel_launch(void* const* d_in, const int* in_sizes, int n_in,
                              void* d_out, int out_size, void* d_ws, size_t ws_size,
                              hipStream_t stream)
{
    const float* x     = (const float*)d_in[0];
    const float* w1    = (const float*)d_in[1];
    const float* b1    = (const float*)d_in[2];
    const float* w2    = (const float*)d_in[3];
    const float* b2    = (const float*)d_in[4];
    const float* w3    = (const float*)d_in[5];
    const float* b3    = (const float*)d_in[6];
    const float* alpha = (const float*)d_in[7];
    float* out = (float*)d_out;

    float* ws = (float*)d_ws;
    float* blocksum = ws;            // 32768
    float* pmin     = ws + 32768;    // 1024
    float* pmax     = ws + 33792;    // 1024
    float* gmin     = ws + 34816;    // 32
    float* gmax     = ws + 34848;    // 32
    float* lut      = ws + 34880;    // 1024

    k_stats <<<NIMG * 32, 256, 0, stream>>>(x, blocksum, pmin, pmax);
    k_minmax<<<NIMG,      64,  0, stream>>>(pmin, pmax, gmin, gmax);
    k_lut   <<<1,         256, 0, stream>>>(blocksum, gmin, gmax,
                                            w1, b1, w2, b2, w3, b3, lut);
    k_apply <<<NIMG * 64, 256, 0, stream>>>(x, gmin, gmax, lut, alpha, out);
}

// Round 2
// 90.779 us; speedup vs baseline: 6.7383x; 6.7383x over previous
//
#include <hip/hip_runtime.h>
#include <math.h>

#define NBINS   64
#define GROUPS  16
#define HIDDEN  128
#define EPSF    1e-6f

// B=2, C=16, H=W=1024; 32 images of 1M floats; 32x32 tiles of 32x32 elems.
#define IMG_ELEMS   (1024*1024)
#define F4_PER_ROW  256          // 1024 cols / 4
#define NIMG        32           // B*C

// ---------------------------------------------------------------------------
// Kernel 1: per image-row-chunk (32 rows): min/max partials + 32 tile sums.
// grid = NIMG*32 blocks, 256 threads.
// ---------------------------------------------------------------------------
__global__ __launch_bounds__(256) void k_stats(
        const float* __restrict__ x,
        float* __restrict__ blocksum,   // [NIMG][32][32] tile sums
        float* __restrict__ pmin,       // [NIMG*32]
        float* __restrict__ pmax)       // [NIMG*32]
{
    const int bid = blockIdx.x;
    const int bc  = bid >> 5;   // image
    const int i   = bid & 31;   // row-chunk (tile row)
    const int t   = threadIdx.x;

    const float4* xin = (const float4*)(x + (size_t)bc * IMG_ELEMS);
    const int rowbase = (i * 32) * F4_PER_ROW;

    float s = 0.f, mn = INFINITY, mx = -INFINITY;
    #pragma unroll 4
    for (int r = 0; r < 32; ++r) {
        float4 v = xin[rowbase + r * F4_PER_ROW + t];
        s += (v.x + v.y) + (v.z + v.w);
        mn = fminf(mn, fminf(fminf(v.x, v.y), fminf(v.z, v.w)));
        mx = fmaxf(mx, fmaxf(fmaxf(v.x, v.y), fmaxf(v.z, v.w)));
    }

    __shared__ float ssum[256], smin[256], smax[256];
    ssum[t] = s; smin[t] = mn; smax[t] = mx;
    __syncthreads();

    // tile-sum reduce: 8 consecutive threads share tile j = t>>3
    if ((t & 7) < 4) ssum[t] += ssum[t + 4];
    __syncthreads();
    if ((t & 7) < 2) ssum[t] += ssum[t + 2];
    __syncthreads();
    if ((t & 7) == 0) {
        float tot = ssum[t] + ssum[t + 1];
        blocksum[bc * 1024 + i * 32 + (t >> 3)] = tot;
    }

    // block-wide min/max
    for (int st = 128; st > 0; st >>= 1) {
        __syncthreads();
        if (t < st) {
            smin[t] = fminf(smin[t], smin[t + st]);
            smax[t] = fmaxf(smax[t], smax[t + st]);
        }
    }
    __syncthreads();
    if (t == 0) { pmin[bid] = smin[0]; pmax[bid] = smax[0]; }
}

// ---------------------------------------------------------------------------
// Kernel 2: reduce 32 partials per image. grid = NIMG blocks, 64 threads.
// ---------------------------------------------------------------------------
__global__ __launch_bounds__(64) void k_minmax(
        const float* __restrict__ pmin, const float* __restrict__ pmax,
        float* __restrict__ gmin, float* __restrict__ gmax)
{
    const int bc = blockIdx.x;
    const int l  = threadIdx.x;
    float mn = pmin[bc * 32 + (l & 31)];
    float mx = pmax[bc * 32 + (l & 31)];
    #pragma unroll
    for (int st = 32; st > 0; st >>= 1) {
        mn = fminf(mn, __shfl_xor(mn, st, 64));
        mx = fmaxf(mx, __shfl_xor(mx, st, 64));
    }
    if (l == 0) { gmin[bc] = mn; gmax[bc] = mx; }
}

// ---------------------------------------------------------------------------
// Kernel 3: per-(b,g) histogram via wave ballots (no atomics) -> scaled cdf.
// grid = 32 blocks (bc = b*16+g), 256 threads. Writes pcdf[b][g][64] already
// pre-scaled by 0.5/ (1024+eps) so consumer just adds the two b-halves.
// ---------------------------------------------------------------------------
__global__ __launch_bounds__(256) void k_hist(
        const float* __restrict__ blocksum,
        const float* __restrict__ gmin, const float* __restrict__ gmax,
        float* __restrict__ pcdf)       // [2][16][64]
{
    const int bc   = blockIdx.x;
    const int t    = threadIdx.x;
    const int lane = t & 63;
    const int wave = t >> 6;

    const float mnv = gmin[bc];
    const float inv = 1.0f / (gmax[bc] - mnv + EPSF);

    int idx0, idx1, idx2, idx3;
    {
        const float* bs = blocksum + bc * 1024;
        #define MKIDX(D, IT) { \
            float bmean = bs[t + (IT)*256] * (1.0f / 1024.0f); \
            float xs = (bmean - mnv) * inv; \
            int id = (int)rintf(xs * 63.0f); \
            D = max(0, min(id, 63)); }
        MKIDX(idx0, 0) MKIDX(idx1, 1) MKIDX(idx2, 2) MKIDX(idx3, 3)
        #undef MKIDX
    }

    // lane l accumulates count of bin l within this wave
    int cnt = 0;
    #pragma unroll 1
    for (int b = 0; b < NBINS; ++b) {
        unsigned long long m0 = __ballot(idx0 == b);
        unsigned long long m1 = __ballot(idx1 == b);
        unsigned long long m2 = __ballot(idx2 == b);
        unsigned long long m3 = __ballot(idx3 == b);
        int p = __popcll(m0) + __popcll(m1) + __popcll(m2) + __popcll(m3);
        cnt += (lane == b) ? p : 0;
    }

    __shared__ int whist[4][NBINS];
    whist[wave][lane] = cnt;
    __syncthreads();

    if (t < NBINS) {
        int h = whist[0][t] + whist[1][t] + whist[2][t] + whist[3][t];
        // inclusive scan over 64 bins (lane == bin)
        #pragma unroll
        for (int d = 1; d < 64; d <<= 1) {
            int v = __shfl_up(h, d, 64);
            if (t >= d) h += v;
        }
        const float scale = 0.5f / (1024.0f + EPSF);   // mean over B pre-applied
        pcdf[bc * NBINS + t] = (float)h * scale;
    }
}

// ---------------------------------------------------------------------------
// Kernel 4: conv1 (16->128ch, 5 taps, ReLU) + depthwise conv2 (5 taps, ReLU).
// grid = 32 blocks, each owns 4 output channels; 256 threads = 4ch x 64 bins.
// Weights staged in LDS; per-wave reads are uniform (broadcast, free).
// ---------------------------------------------------------------------------
__global__ __launch_bounds__(256) void k_conv12(
        const float* __restrict__ pcdf,
        const float* __restrict__ w1, const float* __restrict__ b1,
        const float* __restrict__ w2, const float* __restrict__ b2,
        float* __restrict__ h2)         // [128][64]
{
    __shared__ float dcdf[GROUPS][NBINS];
    __shared__ float w1s[4 * GROUPS * 5];
    __shared__ float w2s[4][5];
    __shared__ float h1s[4][NBINS + 4];  // halo of 2 each side

    const int t   = threadIdx.x;
    const int ocb = blockIdx.x * 4;
    const int ocl = t >> 6;              // wave-uniform
    const int k   = t & 63;

    // dcdf = sum of the two pre-scaled b-halves
    for (int o = t; o < GROUPS * NBINS; o += 256)
        ((float*)dcdf)[o] = pcdf[o] + pcdf[GROUPS * NBINS + o];

    // conv1 weights, kh=2 row only: [ocl][ic][tap]
    for (int o = t; o < 4 * GROUPS * 5; o += 256) {
        const int oo  = o / 80;
        const int rem = o - oo * 80;
        const int ic  = rem / 5;
        const int tap = rem - ic * 5;
        w1s[o] = w1[((ocb + oo) * GROUPS + ic) * 25 + 10 + tap];
    }
    if (t < 20) w2s[t / 5][t % 5] = w2[(ocb + t / 5) * 25 + 10 + t % 5];
    if (t < 4)  { h1s[t][0] = 0.f; h1s[t][1] = 0.f;
                  h1s[t][NBINS + 2] = 0.f; h1s[t][NBINS + 3] = 0.f; }
    __syncthreads();

    // conv1: 80 MACs per thread
    float acc = b1[ocb + ocl];
    const float* wrow = w1s + ocl * 80;
    for (int ic = 0; ic < GROUPS; ++ic) {
        #pragma unroll
        for (int tap = 0; tap < 5; ++tap) {
            const int kk = k - 2 + tap;
            if (kk >= 0 && kk < NBINS)
                acc += wrow[ic * 5 + tap] * dcdf[ic][kk];
        }
    }
    h1s[ocl][k + 2] = fmaxf(acc, 0.f);
    __syncthreads();

    // conv2: depthwise 5 taps over h1 row (halo = 0 handles borders)
    float a = b2[ocb + ocl];
    #pragma unroll
    for (int tap = 0; tap < 5; ++tap)
        a += w2s[ocl][tap] * h1s[ocl][k + tap];
    h2[(ocb + ocl) * NBINS + k] = fmaxf(a, 0.f);
}

// ---------------------------------------------------------------------------
// Kernel 5: conv3 (1x1, 128->16) + softplus + cumsum + normalize + ramp.
// 1 block, 256 threads. h2 (32KB) + w3 (8KB) staged in LDS.
// ---------------------------------------------------------------------------
__global__ __launch_bounds__(256) void k_tail(
        const float* __restrict__ h2,
        const float* __restrict__ w3, const float* __restrict__ b3,
        float* __restrict__ lut)
{
    __shared__ float h2s[HIDDEN][NBINS];
    __shared__ float w3s[GROUPS * HIDDEN];
    __shared__ float sd[GROUPS][NBINS];
    const int t = threadIdx.x;

    for (int o = t; o < HIDDEN * NBINS; o += 256) ((float*)h2s)[o] = h2[o];
    for (int o = t; o < GROUPS * HIDDEN; o += 256) w3s[o] = w3[o];
    __syncthreads();

    const int k = t & 63;      // same k for all 4 of this thread's outputs
    float acc0 = b3[(t >> 6) + 0];
    float acc1 = b3[(t >> 6) + 4];
    float acc2 = b3[(t >> 6) + 8];
    float acc3 = b3[(t >> 6) + 12];
    const int g0 = t >> 6;
    for (int h = 0; h < HIDDEN; ++h) {
        const float v = h2s[h][k];
        acc0 += w3s[(g0 + 0) * HIDDEN + h] * v;
        acc1 += w3s[(g0 + 4) * HIDDEN + h] * v;
        acc2 += w3s[(g0 + 8) * HIDDEN + h] * v;
        acc3 += w3s[(g0 + 12) * HIDDEN + h] * v;
    }
    #define SOFTPLUS(z) (fmaxf(z, 0.f) + log1pf(expf(-fabsf(z))))
    sd[g0 + 0][k]  = SOFTPLUS(acc0);
    sd[g0 + 4][k]  = SOFTPLUS(acc1);
    sd[g0 + 8][k]  = SOFTPLUS(acc2);
    sd[g0 + 12][k] = SOFTPLUS(acc3);
    #undef SOFTPLUS
    __syncthreads();

    if (t < GROUPS) {
        float run = 0.f;
        for (int kk = 0; kk < NBINS; ++kk) { run += sd[t][kk]; sd[t][kk] = run; }
        const float invn = 1.0f / (run + EPSF);
        for (int kk = 0; kk < NBINS; ++kk)
            lut[t * NBINS + kk] = sd[t][kk] * invn + (float)kk * (1.0f / 63.0f);
    }
}

// ---------------------------------------------------------------------------
// Kernel 6: elementwise remap. grid = NIMG*64 blocks, 256 threads,
// 16 float4 per thread. LUT row (64 floats) in LDS.
// ---------------------------------------------------------------------------
__device__ __forceinline__ float remap1(float v, float mnv, float inv, float r,
                                        float aa, const float* lut_s)
{
    float x01 = (v - mnv) * inv;
    float pos = x01 * 63.0f;
    int il = (int)floorf(pos);
    il = max(0, min(il, 63));
    const int ih = min(il + 1, 63);
    const float w = pos - (float)il;
    const float vlo = lut_s[il];
    const float vhi = lut_s[ih];
    const float xe = fmaf(w, vhi - vlo, vlo);
    const float o01 = aa * xe + (1.0f - aa) * x01;
    return o01 * r + mnv;
}

__global__ __launch_bounds__(256) void k_apply(
        const float* __restrict__ x,
        const float* __restrict__ gmin, const float* __restrict__ gmax,
        const float* __restrict__ lut, const float* __restrict__ alpha,
        float* __restrict__ out)
{
    const int img  = blockIdx.x >> 6;
    const int part = blockIdx.x & 63;
    const int c    = img & 15;
    const int t    = threadIdx.x;

    __shared__ float lut_s[NBINS];
    if (t < NBINS) lut_s[t] = lut[c * NBINS + t];
    __syncthreads();

    const float mnv = gmin[img];
    const float mxv = gmax[img];
    const float r   = mxv - mnv;
    const float inv = 1.0f / (r + EPSF);
    const float aa  = 1.0f / (1.0f + expf(-alpha[0]));

    const size_t base4 = (size_t)img * (IMG_ELEMS / 4) + (size_t)part * 4096;
    const float4* xin = (const float4*)x;
    float4* o4 = (float4*)out;

    #pragma unroll 2
    for (int it = 0; it < 16; ++it) {
        const size_t f = base4 + (size_t)t + (size_t)it * 256;
        float4 v = xin[f];
        float4 w;
        w.x = remap1(v.x, mnv, inv, r, aa, lut_s);
        w.y = remap1(v.y, mnv, inv, r, aa, lut_s);
        w.z = remap1(v.z, mnv, inv, r, aa, lut_s);
        w.w = remap1(v.w, mnv, inv, r, aa, lut_s);
        o4[f] = w;
    }
}

// ---------------------------------------------------------------------------
extern "C" void kernel_launch(void* const* d_in, const int* in_sizes, int n_in,
                              void* d_out, int out_size, void* d_ws, size_t ws_size,
                              hipStream_t stream)
{
    const float* x     = (const float*)d_in[0];
    const float* w1    = (const float*)d_in[1];
    const float* b1    = (const float*)d_in[2];
    const float* w2    = (const float*)d_in[3];
    const float* b2    = (const float*)d_in[4];
    const float* w3    = (const float*)d_in[5];
    const float* b3    = (const float*)d_in[6];
    const float* alpha = (const float*)d_in[7];
    float* out = (float*)d_out;

    float* ws = (float*)d_ws;
    float* blocksum = ws;            // 32768
    float* pmin     = ws + 32768;    // 1024
    float* pmax     = ws + 33792;    // 1024
    float* gmin     = ws + 34816;    // 32
    float* gmax     = ws + 34848;    // 32
    float* lut      = ws + 34880;    // 1024
    float* pcdf     = ws + 35904;    // 2048
    float* h2       = ws + 37952;    // 8192

    k_stats <<<NIMG * 32, 256, 0, stream>>>(x, blocksum, pmin, pmax);
    k_minmax<<<NIMG,      64,  0, stream>>>(pmin, pmax, gmin, gmax);
    k_hist  <<<NIMG,      256, 0, stream>>>(blocksum, gmin, gmax, pcdf);
    k_conv12<<<32,        256, 0, stream>>>(pcdf, w1, b1, w2, b2, h2);
    k_tail  <<<1,         256, 0, stream>>>(h2, w3, b3, lut);
    k_apply <<<NIMG * 64, 256, 0, stream>>>(x, gmin, gmax, lut, alpha, out);
}

// Round 4
// 88.030 us; speedup vs baseline: 6.9488x; 1.0312x over previous
//
#include <hip/hip_runtime.h>
#include <math.h>

#define NBINS   64
#define GROUPS  16
#define HIDDEN  128
#define EPSF    1e-6f

// B=2, C=16, H=W=1024; 32 images of 1M floats; 32x32 tiles of 32x32 elems.
#define IMG_ELEMS   (1024*1024)
#define F4_PER_ROW  256          // 1024 cols / 4
#define NIMG        32           // B*C

typedef float nfloat4 __attribute__((ext_vector_type(4)));  // builtin-compatible

// ---------------------------------------------------------------------------
// Kernel 1: per image-row-chunk (32 rows): min/max partials + 32 tile sums.
// grid = NIMG*32 blocks, 256 threads.
// ---------------------------------------------------------------------------
__global__ __launch_bounds__(256) void k_stats(
        const float* __restrict__ x,
        float* __restrict__ blocksum,   // [NIMG][32][32] tile sums
        float* __restrict__ pmin,       // [NIMG*32]
        float* __restrict__ pmax)       // [NIMG*32]
{
    const int bid = blockIdx.x;
    const int bc  = bid >> 5;   // image
    const int i   = bid & 31;   // row-chunk (tile row)
    const int t   = threadIdx.x;
    const int lane = t & 63;
    const int wave = t >> 6;

    const float4* xin = (const float4*)(x + (size_t)bc * IMG_ELEMS);
    const int rowbase = (i * 32) * F4_PER_ROW;

    float s = 0.f, mn = INFINITY, mx = -INFINITY;
    #pragma unroll 4
    for (int r = 0; r < 32; ++r) {
        float4 v = xin[rowbase + r * F4_PER_ROW + t];
        s += (v.x + v.y) + (v.z + v.w);
        mn = fminf(mn, fminf(fminf(v.x, v.y), fminf(v.z, v.w)));
        mx = fmaxf(mx, fmaxf(fmaxf(v.x, v.y), fmaxf(v.z, v.w)));
    }

    // tile sums: 8 consecutive threads share tile j = t>>3 (within a wave)
    s += __shfl_xor(s, 4, 64);
    s += __shfl_xor(s, 2, 64);
    s += __shfl_xor(s, 1, 64);
    if ((t & 7) == 0)
        blocksum[bc * 1024 + i * 32 + (t >> 3)] = s;

    // block-wide min/max: wave shuffle reduce, then cross-wave via LDS
    #pragma unroll
    for (int st = 32; st > 0; st >>= 1) {
        mn = fminf(mn, __shfl_xor(mn, st, 64));
        mx = fmaxf(mx, __shfl_xor(mx, st, 64));
    }
    __shared__ float wmn[4], wmx[4];
    if (lane == 0) { wmn[wave] = mn; wmx[wave] = mx; }
    __syncthreads();
    if (t == 0) {
        pmin[bid] = fminf(fminf(wmn[0], wmn[1]), fminf(wmn[2], wmn[3]));
        pmax[bid] = fmaxf(fmaxf(wmx[0], wmx[1]), fmaxf(wmx[2], wmx[3]));
    }
}

// ---------------------------------------------------------------------------
// Kernel 2: fused per-image min/max finalize + histogram via wave ballots
// (no atomics) -> scaled cdf. grid = 32 blocks (bc = b*16+g), 256 threads.
// ---------------------------------------------------------------------------
__global__ __launch_bounds__(256) void k_hist(
        const float* __restrict__ pmin, const float* __restrict__ pmax,
        const float* __restrict__ blocksum,
        float* __restrict__ gmin, float* __restrict__ gmax,
        float* __restrict__ pcdf)       // [2][16][64]
{
    const int bc   = blockIdx.x;
    const int t    = threadIdx.x;
    const int lane = t & 63;
    const int wave = t >> 6;

    __shared__ float s_mn, s_inv;
    if (wave == 0) {
        float mn = (lane < 32) ? pmin[bc * 32 + lane] : INFINITY;
        float mx = (lane < 32) ? pmax[bc * 32 + lane] : -INFINITY;
        #pragma unroll
        for (int st = 32; st > 0; st >>= 1) {
            mn = fminf(mn, __shfl_xor(mn, st, 64));
            mx = fmaxf(mx, __shfl_xor(mx, st, 64));
        }
        if (lane == 0) {
            gmin[bc] = mn; gmax[bc] = mx;
            s_mn = mn; s_inv = 1.0f / (mx - mn + EPSF);
        }
    }
    __syncthreads();
    const float mnv = s_mn;
    const float inv = s_inv;

    int idx0, idx1, idx2, idx3;
    {
        const float* bs = blocksum + bc * 1024;
        #define MKIDX(D, IT) { \
            float bmean = bs[t + (IT)*256] * (1.0f / 1024.0f); \
            float xs = (bmean - mnv) * inv; \
            int id = (int)rintf(xs * 63.0f); \
            D = max(0, min(id, 63)); }
        MKIDX(idx0, 0) MKIDX(idx1, 1) MKIDX(idx2, 2) MKIDX(idx3, 3)
        #undef MKIDX
    }

    // lane l accumulates count of bin l within this wave
    int cnt = 0;
    #pragma unroll 1
    for (int b = 0; b < NBINS; ++b) {
        unsigned long long m0 = __ballot(idx0 == b);
        unsigned long long m1 = __ballot(idx1 == b);
        unsigned long long m2 = __ballot(idx2 == b);
        unsigned long long m3 = __ballot(idx3 == b);
        int p = __popcll(m0) + __popcll(m1) + __popcll(m2) + __popcll(m3);
        cnt += (lane == b) ? p : 0;
    }

    __shared__ int whist[4][NBINS];
    whist[wave][lane] = cnt;
    __syncthreads();

    if (t < NBINS) {
        int h = whist[0][t] + whist[1][t] + whist[2][t] + whist[3][t];
        // inclusive scan over 64 bins (lane == bin)
        #pragma unroll
        for (int d = 1; d < 64; d <<= 1) {
            int v = __shfl_up(h, d, 64);
            if (t >= d) h += v;
        }
        const float scale = 0.5f / (1024.0f + EPSF);   // mean over B pre-applied
        pcdf[bc * NBINS + t] = (float)h * scale;
    }
}

// ---------------------------------------------------------------------------
// Kernel 3: conv1 (16->128ch, 5 taps, ReLU) + depthwise conv2 (5 taps, ReLU).
// grid = 32 blocks, each owns 4 output channels; 256 threads = 4ch x 64 bins.
// ---------------------------------------------------------------------------
__global__ __launch_bounds__(256) void k_conv12(
        const float* __restrict__ pcdf,
        const float* __restrict__ w1, const float* __restrict__ b1,
        const float* __restrict__ w2, const float* __restrict__ b2,
        float* __restrict__ h2)         // [128][64]
{
    __shared__ float dcdf[GROUPS][NBINS];
    __shared__ float w1s[4 * GROUPS * 5];
    __shared__ float w2s[4][5];
    __shared__ float h1s[4][NBINS + 4];  // halo of 2 each side

    const int t   = threadIdx.x;
    const int ocb = blockIdx.x * 4;
    const int ocl = t >> 6;              // wave-uniform
    const int k   = t & 63;

    // dcdf = sum of the two pre-scaled b-halves
    for (int o = t; o < GROUPS * NBINS; o += 256)
        ((float*)dcdf)[o] = pcdf[o] + pcdf[GROUPS * NBINS + o];

    // conv1 weights, kh=2 row only: [ocl][ic][tap]
    for (int o = t; o < 4 * GROUPS * 5; o += 256) {
        const int oo  = o / 80;
        const int rem = o - oo * 80;
        const int ic  = rem / 5;
        const int tap = rem - ic * 5;
        w1s[o] = w1[((ocb + oo) * GROUPS + ic) * 25 + 10 + tap];
    }
    if (t < 20) w2s[t / 5][t % 5] = w2[(ocb + t / 5) * 25 + 10 + t % 5];
    if (t < 4)  { h1s[t][0] = 0.f; h1s[t][1] = 0.f;
                  h1s[t][NBINS + 2] = 0.f; h1s[t][NBINS + 3] = 0.f; }
    __syncthreads();

    // conv1: 80 MACs per thread
    float acc = b1[ocb + ocl];
    const float* wrow = w1s + ocl * 80;
    for (int ic = 0; ic < GROUPS; ++ic) {
        #pragma unroll
        for (int tap = 0; tap < 5; ++tap) {
            const int kk = k - 2 + tap;
            if (kk >= 0 && kk < NBINS)
                acc += wrow[ic * 5 + tap] * dcdf[ic][kk];
        }
    }
    h1s[ocl][k + 2] = fmaxf(acc, 0.f);
    __syncthreads();

    // conv2: depthwise 5 taps over h1 row (halo = 0 handles borders)
    float a = b2[ocb + ocl];
    #pragma unroll
    for (int tap = 0; tap < 5; ++tap)
        a += w2s[ocl][tap] * h1s[ocl][k + tap];
    h2[(ocb + ocl) * NBINS + k] = fmaxf(a, 0.f);
}

// ---------------------------------------------------------------------------
// Kernel 4: conv3 (1x1, 128->16) + softplus + cumsum + normalize + ramp.
// 1 block, 256 threads. h2 (32KB) + w3 (8KB) staged in LDS.
// ---------------------------------------------------------------------------
__global__ __launch_bounds__(256) void k_tail(
        const float* __restrict__ h2,
        const float* __restrict__ w3, const float* __restrict__ b3,
        float* __restrict__ lut)
{
    __shared__ float h2s[HIDDEN][NBINS];
    __shared__ float w3s[GROUPS * HIDDEN];
    __shared__ float sd[GROUPS][NBINS];
    const int t = threadIdx.x;

    for (int o = t; o < HIDDEN * NBINS; o += 256) ((float*)h2s)[o] = h2[o];
    for (int o = t; o < GROUPS * HIDDEN; o += 256) w3s[o] = w3[o];
    __syncthreads();

    const int k = t & 63;
    const int g0 = t >> 6;
    float acc0 = b3[g0 + 0];
    float acc1 = b3[g0 + 4];
    float acc2 = b3[g0 + 8];
    float acc3 = b3[g0 + 12];
    for (int h = 0; h < HIDDEN; ++h) {
        const float v = h2s[h][k];
        acc0 += w3s[(g0 + 0) * HIDDEN + h] * v;
        acc1 += w3s[(g0 + 4) * HIDDEN + h] * v;
        acc2 += w3s[(g0 + 8) * HIDDEN + h] * v;
        acc3 += w3s[(g0 + 12) * HIDDEN + h] * v;
    }
    #define SOFTPLUS(z) (fmaxf(z, 0.f) + log1pf(expf(-fabsf(z))))
    sd[g0 + 0][k]  = SOFTPLUS(acc0);
    sd[g0 + 4][k]  = SOFTPLUS(acc1);
    sd[g0 + 8][k]  = SOFTPLUS(acc2);
    sd[g0 + 12][k] = SOFTPLUS(acc3);
    #undef SOFTPLUS
    __syncthreads();

    if (t < GROUPS) {
        float run = 0.f;
        for (int kk = 0; kk < NBINS; ++kk) { run += sd[t][kk]; sd[t][kk] = run; }
        const float invn = 1.0f / (run + EPSF);
        for (int kk = 0; kk < NBINS; ++kk)
            lut[t * NBINS + kk] = sd[t][kk] * invn + (float)kk * (1.0f / 63.0f);
    }
}

// ---------------------------------------------------------------------------
// Kernel 5: elementwise remap. grid = NIMG*64 blocks, 256 threads,
// 16 float4 per thread. LUT row (64 floats) in LDS. Output uses NONTEMPORAL
// stores (L3 bypass) so x (128MB) stays resident in the 256MB Infinity Cache.
// ---------------------------------------------------------------------------
__device__ __forceinline__ float remap1(float v, float mnv, float inv, float r,
                                        float aa, const float* lut_s)
{
    float x01 = (v - mnv) * inv;
    float pos = x01 * 63.0f;
    int il = (int)floorf(pos);
    il = max(0, min(il, 63));
    const int ih = min(il + 1, 63);
    const float w = pos - (float)il;
    const float vlo = lut_s[il];
    const float vhi = lut_s[ih];
    const float xe = fmaf(w, vhi - vlo, vlo);
    const float o01 = aa * xe + (1.0f - aa) * x01;
    return o01 * r + mnv;
}

__global__ __launch_bounds__(256) void k_apply(
        const float* __restrict__ x,
        const float* __restrict__ gmin, const float* __restrict__ gmax,
        const float* __restrict__ lut, const float* __restrict__ alpha,
        float* __restrict__ out)
{
    const int img  = blockIdx.x >> 6;
    const int part = blockIdx.x & 63;
    const int c    = img & 15;
    const int t    = threadIdx.x;

    __shared__ float lut_s[NBINS];
    if (t < NBINS) lut_s[t] = lut[c * NBINS + t];
    __syncthreads();

    const float mnv = gmin[img];
    const float mxv = gmax[img];
    const float r   = mxv - mnv;
    const float inv = 1.0f / (r + EPSF);
    const float aa  = 1.0f / (1.0f + expf(-alpha[0]));

    const size_t base4 = (size_t)img * (IMG_ELEMS / 4) + (size_t)part * 4096;
    const float4* xin = (const float4*)x;
    nfloat4* o4 = (nfloat4*)out;

    #pragma unroll 2
    for (int it = 0; it < 16; ++it) {
        const size_t f = base4 + (size_t)t + (size_t)it * 256;
        float4 v = xin[f];
        nfloat4 w;
        w.x = remap1(v.x, mnv, inv, r, aa, lut_s);
        w.y = remap1(v.y, mnv, inv, r, aa, lut_s);
        w.z = remap1(v.z, mnv, inv, r, aa, lut_s);
        w.w = remap1(v.w, mnv, inv, r, aa, lut_s);
        __builtin_nontemporal_store(w, &o4[f]);
    }
}

// ---------------------------------------------------------------------------
extern "C" void kernel_launch(void* const* d_in, const int* in_sizes, int n_in,
                              void* d_out, int out_size, void* d_ws, size_t ws_size,
                              hipStream_t stream)
{
    const float* x     = (const float*)d_in[0];
    const float* w1    = (const float*)d_in[1];
    const float* b1    = (const float*)d_in[2];
    const float* w2    = (const float*)d_in[3];
    const float* b2    = (const float*)d_in[4];
    const float* w3    = (const float*)d_in[5];
    const float* b3    = (const float*)d_in[6];
    const float* alpha = (const float*)d_in[7];
    float* out = (float*)d_out;

    float* ws = (float*)d_ws;
    float* blocksum = ws;            // 32768
    float* pmin     = ws + 32768;    // 1024
    float* pmax     = ws + 33792;    // 1024
    float* gmin     = ws + 34816;    // 32
    float* gmax     = ws + 34848;    // 32
    float* lut      = ws + 34880;    // 1024
    float* pcdf     = ws + 35904;    // 2048
    float* h2       = ws + 37952;    // 8192

    k_stats <<<NIMG * 32, 256, 0, stream>>>(x, blocksum, pmin, pmax);
    k_hist  <<<NIMG,      256, 0, stream>>>(pmin, pmax, blocksum, gmin, gmax, pcdf);
    k_conv12<<<32,        256, 0, stream>>>(pcdf, w1, b1, w2, b2, h2);
    k_tail  <<<1,         256, 0, stream>>>(h2, w3, b3, lut);
    k_apply <<<NIMG * 64, 256, 0, stream>>>(x, gmin, gmax, lut, alpha, out);
}